// Round 3
// baseline (232.155 us; speedup 1.0000x reference)
//
#include <hip/hip_runtime.h>
#include <hip/hip_cooperative_groups.h>
#include <math.h>

namespace cg = cooperative_groups;

#define HXc 3.0f
#define HZc 0.25f
#define JZc (-1.0f)

// ws layout (float offsets)
#define OFF_COSR 0         // [256*256] cos(theta) row-major [m][l]
#define OFF_SINR 65536
#define OFF_COST 131072    // [256*256] transposed [l][m]
#define OFF_SINT 196608
#define OFF_NM   262144    // [256] per-m sum_b base*F
#define OFF_DM   262400    // [256] per-m sum_b base

// One cooperative kernel: 256 blocks (block = m) x 1024 threads (16 waves).
__global__ __launch_bounds__(1024) void k_all(
        const float* __restrict__ theta,
        const float* __restrict__ coef,
        const float* __restrict__ strengths,
        float* __restrict__ ws,
        float* __restrict__ out) {
    cg::grid_group grid = cg::this_grid();

    int m = blockIdx.x;
    int tid = threadIdx.x;

    float* __restrict__ cosR = ws + OFF_COSR;
    float* __restrict__ sinR = ws + OFF_SINR;
    float* __restrict__ cosT = ws + OFF_COST;
    float* __restrict__ sinT = ws + OFF_SINT;
    float* __restrict__ Nm = ws + OFF_NM;
    float* __restrict__ Dm = ws + OFF_DM;

    __shared__ float sLDS[256];          // strengths, padded (s[255]=0)
    __shared__ float4 quart[4][256];     // phase-A partials (p,u,v,z)
    __shared__ float Flds[256], cPlds[256];
    __shared__ float wr[4][4];
    __shared__ float gN[16 * 256];
    __shared__ float gD[16 * 256];
    __shared__ float snL[256], sdL[256]; // per-(m,l) gradient sums (unscaled)
    __shared__ float scal[4];            // cN_m, cD_m, E, invD

    // ---- Stage 0: sincos tables (block m does row m) + strengths to LDS ----
    if (tid < 256) {
        sLDS[tid] = (tid < 255) ? strengths[tid] : 0.0f;
        int i = m * 256 + tid;
        float s, c;
        sincosf(theta[i], &s, &c);
        cosR[i] = c;
        sinR[i] = s;
        cosT[tid * 256 + m] = c;
        sinT[tid * 256 + m] = s;
    }
    grid.sync();

    // ---- Phase A: forward. thread -> (quarter q, column b) ----
    {
        int b = tid & 255, q = tid >> 8;
        int l0 = q * 64;
        float p = 1.0f, u = 0.0f, v = 0.0f, z = 0.0f, a_prev = 0.0f;
        if (q) {
            int l = l0 - 1;
            float cmv = cosT[l * 256 + m], smv = sinT[l * 256 + m];
            float cbv = cosT[l * 256 + b], sbv = sinT[l * 256 + b];
            float t1 = cmv * cbv, t2 = smv * sbv;
            a_prev = (t1 - t2) * __builtin_amdgcn_rcpf(t1 + t2);
        }
        for (int l = l0; l < l0 + 64; ++l) {
            float cmv = cosT[l * 256 + m], smv = sinT[l * 256 + m]; // uniform
            float cbv = cosT[l * 256 + b], sbv = sinT[l * 256 + b]; // coalesced
            float t1 = cmv * cbv, t2 = smv * sbv;
            float t3 = smv * cbv, t4 = cmv * sbv;
            float cosd = t1 + t2;
            float coss = t1 - t2;
            float sins = t3 + t4;
            float inv = __builtin_amdgcn_rcpf(cosd);
            p *= cosd;
            u = fmaf(sins, inv, u);
            float a = coss * inv;
            v += a;
            float sPrev = (l > 0) ? sLDS[l - 1] : 0.0f;
            z = fmaf(sPrev * a_prev, a, z);
            a_prev = a;
        }
        quart[q][b] = make_float4(p, u, v, z);
    }
    __syncthreads();

    // ---- Combine quarters: F/cP to LDS, per-m reductions to global ----
    if (tid < 256) {
        float4 A = quart[0][tid], B = quart[1][tid];
        float4 C = quart[2][tid], Dq = quart[3][tid];
        float P = A.x * B.x * C.x * Dq.x;
        float U = A.y + B.y + C.y + Dq.y;
        float V = A.z + B.z + C.z + Dq.z;
        float Z = A.w + B.w + C.w + Dq.w;
        float F = HZc * V + HXc * U + JZc * Z;
        float cP = coef[tid] * P;
        Flds[tid] = F;
        cPlds[tid] = cP;
        float coefm = coef[m];
        float base = coefm * cP;
        float s1 = base, s2 = base * F, s3 = cP, s4 = cP * F;
        for (int o = 32; o; o >>= 1) {
            s1 += __shfl_xor(s1, o);
            s2 += __shfl_xor(s2, o);
            s3 += __shfl_xor(s3, o);
            s4 += __shfl_xor(s4, o);
        }
        if ((tid & 63) == 0) {
            int w = tid >> 6;
            wr[w][0] = s1; wr[w][1] = s2; wr[w][2] = s3; wr[w][3] = s4;
        }
    }
    __syncthreads();
    if (tid == 0) {
        Dm[m] = wr[0][0] + wr[1][0] + wr[2][0] + wr[3][0];
        Nm[m] = wr[0][1] + wr[1][1] + wr[2][1] + wr[3][1];
        scal[1] = wr[0][2] + wr[1][2] + wr[2][2] + wr[3][2];  // cD_m
        scal[0] = wr[0][3] + wr[1][3] + wr[2][3] + wr[3][3];  // cN_m
    }

    // ---- Phase B: gradient. wave = 16-b chunk, lane = 4 consecutive l's ----
    {
        int w = tid >> 6, lane = tid & 63;
        int l0 = lane * 4;
        float coefm = coef[m];
        float4 cm4 = *(const float4*)&cosR[m * 256 + l0];
        float4 sm4 = *(const float4*)&sinR[m * 256 + l0];
        float cmv[4] = {cm4.x, cm4.y, cm4.z, cm4.w};
        float smv[4] = {sm4.x, sm4.y, sm4.z, sm4.w};
        float sR[4], sL[4];
#pragma unroll
        for (int j = 0; j < 4; ++j) {
            int l = l0 + j;
            sR[j] = sLDS[l];
            sL[j] = (l > 0) ? sLDS[l - 1] : 0.0f;
        }
        float pN[4] = {0.f, 0.f, 0.f, 0.f};
        float pD[4] = {0.f, 0.f, 0.f, 0.f};

        for (int i = 0; i < 16; ++i) {
            int b = w * 16 + i;
            float4 cb4 = *(const float4*)&cosR[b * 256 + l0];
            float4 sb4 = *(const float4*)&sinR[b * 256 + l0];
            float cbv[4] = {cb4.x, cb4.y, cb4.z, cb4.w};
            float sbv[4] = {sb4.x, sb4.y, sb4.z, sb4.w};
            float Fv = Flds[b];
            float base = coefm * cPlds[b];

            float a[4], inv[4], coss[4], sins[4], sind[4];
#pragma unroll
            for (int j = 0; j < 4; ++j) {
                float t1 = cmv[j] * cbv[j], t2 = smv[j] * sbv[j];
                float t3 = smv[j] * cbv[j], t4 = cmv[j] * sbv[j];
                float cosd = t1 + t2;
                coss[j] = t1 - t2;
                sins[j] = t3 + t4;
                sind[j] = t3 - t4;
                inv[j] = __builtin_amdgcn_rcpf(cosd);
                a[j] = coss[j] * inv[j];
            }
            float aLn = __shfl_up(a[3], 1);
            if (lane == 0) aLn = 0.0f;
            float aRn = __shfl_down(a[0], 1);
            if (lane == 63) aRn = 0.0f;
            float am1[4] = {aLn, a[0], a[1], a[2]};
            float ap1[4] = {a[1], a[2], a[3], aRn};
#pragma unroll
            for (int j = 0; j < 4; ++j) {
                float sii = sind[j] * inv[j];
                float g_d = -sii;
                float Gxz = (HXc * coss[j] - HZc * sins[j]) * inv[j]
                          + (HZc * coss[j] + HXc * sins[j]) * (sii * inv[j]);
                float K = JZc * ((coss[j] * sii - sins[j]) * inv[j]);
                float inc = fmaf(sR[j], ap1[j], sL[j] * am1[j]);
                float term = fmaf(Fv, g_d, fmaf(K, inc, Gxz));
                pN[j] = fmaf(base, term, pN[j]);
                pD[j] = fmaf(base, g_d, pD[j]);
            }
        }
        ((float4*)gN)[w * 64 + lane] = make_float4(pN[0], pN[1], pN[2], pN[3]);
        ((float4*)gD)[w * 64 + lane] = make_float4(pD[0], pD[1], pD[2], pD[3]);
    }
    __syncthreads();
    if (tid < 256) {
        float sn = 0.0f, sd = 0.0f;
#pragma unroll
        for (int ww = 0; ww < 16; ++ww) {
            sn += gN[ww * 256 + tid];
            sd += gD[ww * 256 + tid];
        }
        snL[tid] = sn;
        sdL[tid] = sd;
    }
    __threadfence();
    grid.sync();

    // ---- Final: redundant deterministic N/D reduction, scale, store ----
    if (tid < 256) {
        float nv = Nm[tid], dv = Dm[tid];
        for (int o = 32; o; o >>= 1) {
            nv += __shfl_xor(nv, o);
            dv += __shfl_xor(dv, o);
        }
        if ((tid & 63) == 0) {
            int w = tid >> 6;
            wr[w][0] = nv; wr[w][1] = dv;
        }
    }
    __syncthreads();
    if (tid == 0) {
        float N = wr[0][0] + wr[1][0] + wr[2][0] + wr[3][0];
        float D = wr[0][1] + wr[1][1] + wr[2][1] + wr[3][1];
        scal[2] = N / D;
        scal[3] = 1.0f / D;
    }
    __syncthreads();
    float E = scal[2], invD = scal[3];
    if (tid < 256) {
        out[m * 256 + tid] = 2.0f * invD * (snL[tid] - E * sdL[tid]);
    }
    if (tid == 0) {
        out[65536 + m] = 2.0f * invD * (scal[0] - E * scal[1]);
    }
    if (m == 0 && tid == 1) {
        out[65792] = E * (1.0f / 256.0f);
    }
}

extern "C" void kernel_launch(void* const* d_in, const int* in_sizes, int n_in,
                              void* d_out, int out_size, void* d_ws, size_t ws_size,
                              hipStream_t stream) {
    const float* theta = (const float*)d_in[0];
    const float* coef = (const float*)d_in[1];
    const float* strengths = (const float*)d_in[4];
    float* out = (float*)d_out;
    float* ws = (float*)d_ws;

    void* args[] = {(void*)&theta, (void*)&coef, (void*)&strengths,
                    (void*)&ws, (void*)&out};
    hipLaunchCooperativeKernel((const void*)k_all, dim3(256), dim3(1024),
                               args, 0, stream);
}

// Round 4
// 87.936 us; speedup vs baseline: 2.6401x; 2.6401x over previous
//
#include <hip/hip_runtime.h>
#include <math.h>

#define HXc 3.0f
#define HZc 0.25f
#define JZc (-1.0f)

// ws layout (float offsets)
#define OFF_TANR 0         // [256*256] tan(theta) row-major [m][l]
#define OFF_TANT 65536     // [256*256] transposed [l][m]
#define OFF_CPR  131072    // [256] per-row product of cos(theta)
#define OFF_DNT  131328    // [256*256] unscaled dN_dtheta/2
#define OFF_DDT  196864    // [256*256] unscaled dD_dtheta/2
#define OFF_NM   262400    // [256] per-m sum_b base*F
#define OFF_DM   262656    // [256] per-m sum_b base
#define OFF_CN   262912    // [256] per-m sum_b cP*F
#define OFF_CD   263168    // [256] per-m sum_b cP

// block = m, thread = l: tan tables (row + transposed) + per-row cos product.
__global__ __launch_bounds__(256) void k_prep(const float* __restrict__ theta,
                                              float* __restrict__ ws) {
    int m = blockIdx.x, t = threadIdx.x;
    float s, c;
    sincosf(theta[m * 256 + t], &s, &c);
    float tn = s / c;                     // |theta|<0.3 so c>0.95, safe
    ws[OFF_TANR + m * 256 + t] = tn;
    ws[OFF_TANT + t * 256 + m] = tn;
    float pr = c;
    for (int o = 32; o; o >>= 1) pr *= __shfl_xor(pr, o);
    __shared__ float pp[4];
    if ((t & 63) == 0) pp[t >> 6] = pr;
    __syncthreads();
    if (t == 0) ws[OFF_CPR + m] = pp[0] * pp[1] * pp[2] * pp[3];
}

// Block m, 1024 threads (16 waves). Phase A: forward per-b over l-quarters.
// Phase B: gradient, wave = 16-b chunk, lane = 4 consecutive l's.
__global__ __launch_bounds__(1024) void k_main(
        const float* __restrict__ coef,
        const float* __restrict__ strengths,
        float* __restrict__ ws) {
    int m = blockIdx.x;
    int tid = threadIdx.x;
    const float* __restrict__ tanR = ws + OFF_TANR;
    const float* __restrict__ tanT = ws + OFF_TANT;
    const float* __restrict__ Cpr = ws + OFF_CPR;

    __shared__ float sLDS[256];          // strengths, padded (s[255]=0)
    __shared__ float tmL[256];           // tan row m
    __shared__ float4 quart[4][256];     // phase-A partials (pw,u,v,z)
    __shared__ float Flds[256], cPlds[256];
    __shared__ float wr[4][4];
    __shared__ float gN[16 * 256];
    __shared__ float gD[16 * 256];

    if (tid < 256) {
        sLDS[tid] = (tid < 255) ? strengths[tid] : 0.0f;
        tmL[tid] = tanR[m * 256 + tid];
    }
    __syncthreads();

    // ---- Phase A: forward. thread -> (quarter q, column b) ----
    {
        int b = tid & 255, q = tid >> 8;
        int l0 = q * 64;
        float pw = 1.0f, u = 0.0f, v = 0.0f, z = 0.0f, a_prev = 0.0f;
        if (q) {
            int l = l0 - 1;
            float qq = tmL[l] * tanT[l * 256 + b];
            a_prev = (1.0f - qq) * __builtin_amdgcn_rcpf(1.0f + qq);
        }
        for (int l = l0; l < l0 + 64; ++l) {
            float tm = tmL[l];                     // LDS broadcast
            float tb = tanT[l * 256 + b];          // coalesced global
            float qq = tm * tb;
            float w1 = 1.0f + qq;
            float inv = __builtin_amdgcn_rcpf(w1);
            pw *= w1;
            u = fmaf(tm + tb, inv, u);             // sins/cosd
            float a = (1.0f - qq) * inv;           // coss/cosd
            v += a;
            float sPrev = (l > 0) ? sLDS[l - 1] : 0.0f;
            z = fmaf(sPrev * a_prev, a, z);
            a_prev = a;
        }
        quart[q][b] = make_float4(pw, u, v, z);
    }
    __syncthreads();

    // ---- Combine quarters: F/cP to LDS, per-m reductions to global ----
    if (tid < 256) {
        float4 A = quart[0][tid], B = quart[1][tid];
        float4 C = quart[2][tid], Dq = quart[3][tid];
        float P = Cpr[m] * Cpr[tid] * (A.x * B.x * C.x * Dq.x);
        float U = A.y + B.y + C.y + Dq.y;
        float V = A.z + B.z + C.z + Dq.z;
        float Z = A.w + B.w + C.w + Dq.w;
        float F = HZc * V + HXc * U + JZc * Z;
        float cP = coef[tid] * P;
        Flds[tid] = F;
        cPlds[tid] = cP;
        float base = coef[m] * cP;
        float s1 = base, s2 = base * F, s3 = cP, s4 = cP * F;
        for (int o = 32; o; o >>= 1) {
            s1 += __shfl_xor(s1, o);
            s2 += __shfl_xor(s2, o);
            s3 += __shfl_xor(s3, o);
            s4 += __shfl_xor(s4, o);
        }
        if ((tid & 63) == 0) {
            int w = tid >> 6;
            wr[w][0] = s1; wr[w][1] = s2; wr[w][2] = s3; wr[w][3] = s4;
        }
    }
    __syncthreads();
    if (tid == 0) {
        ws[OFF_DM + m] = wr[0][0] + wr[1][0] + wr[2][0] + wr[3][0];
        ws[OFF_NM + m] = wr[0][1] + wr[1][1] + wr[2][1] + wr[3][1];
        ws[OFF_CD + m] = wr[0][2] + wr[1][2] + wr[2][2] + wr[3][2];
        ws[OFF_CN + m] = wr[0][3] + wr[1][3] + wr[2][3] + wr[3][3];
    }

    // ---- Phase B: gradient. wave = 16-b chunk, lane = 4 consecutive l's ----
    {
        int w = tid >> 6, lane = tid & 63;
        int l0 = lane * 4;
        float coefm = coef[m];
        float4 tm4 = *(const float4*)&tmL[l0];
        float tm[4] = {tm4.x, tm4.y, tm4.z, tm4.w};
        float sR[4], sL[4];
#pragma unroll
        for (int j = 0; j < 4; ++j) {
            int l = l0 + j;
            sR[j] = sLDS[l];
            sL[j] = (l > 0) ? sLDS[l - 1] : 0.0f;
        }
        float pN[4] = {0.f, 0.f, 0.f, 0.f};
        float pD[4] = {0.f, 0.f, 0.f, 0.f};

        for (int i = 0; i < 16; ++i) {
            int b = w * 16 + i;
            float4 tb4 = *(const float4*)&tanR[b * 256 + l0];
            float tb[4] = {tb4.x, tb4.y, tb4.z, tb4.w};
            float Fv = Flds[b];                 // LDS broadcast
            float base = coefm * cPlds[b];

            float A[4], S[4], G[4];
#pragma unroll
            for (int j = 0; j < 4; ++j) {
                float qq = tm[j] * tb[j];
                float w1 = 1.0f + qq;
                float inv = __builtin_amdgcn_rcpf(w1);
                A[j] = (1.0f - qq) * inv;       // coss/cosd = a
                S[j] = (tm[j] + tb[j]) * inv;   // sins/cosd
                G[j] = (tm[j] - tb[j]) * inv;   // sind/cosd
            }
            float aLn = __shfl_up(A[3], 1);
            if (lane == 0) aLn = 0.0f;
            float aRn = __shfl_down(A[0], 1);
            if (lane == 63) aRn = 0.0f;
            float am1[4] = {aLn, A[0], A[1], A[2]};
            float ap1[4] = {A[1], A[2], A[3], aRn};
#pragma unroll
            for (int j = 0; j < 4; ++j) {
                float Gxz = fmaf(HXc, A[j], -HZc * S[j])
                          + fmaf(HZc, A[j], HXc * S[j]) * G[j];
                float K = JZc * fmaf(A[j], G[j], -S[j]);
                float inc = fmaf(sR[j], ap1[j], sL[j] * am1[j]);
                float term = fmaf(Fv, -G[j], fmaf(K, inc, Gxz));
                pN[j] = fmaf(base, term, pN[j]);
                pD[j] = fmaf(base, -G[j], pD[j]);
            }
        }
        ((float4*)gN)[w * 64 + lane] = make_float4(pN[0], pN[1], pN[2], pN[3]);
        ((float4*)gD)[w * 64 + lane] = make_float4(pD[0], pD[1], pD[2], pD[3]);
    }
    __syncthreads();
    if (tid < 256) {
        float sn = 0.0f, sd = 0.0f;
#pragma unroll
        for (int ww = 0; ww < 16; ++ww) {
            sn += gN[ww * 256 + tid];
            sd += gD[ww * 256 + tid];
        }
        ws[OFF_DNT + m * 256 + tid] = sn;
        ws[OFF_DDT + m * 256 + tid] = sd;
    }
}

// 256 blocks x 256 thr: redundant (deterministic) N/D reduction, then scale.
__global__ __launch_bounds__(256) void k_fin(const float* __restrict__ ws,
                                             float* __restrict__ out) {
    int m = blockIdx.x, t = threadIdx.x;
    float nv = ws[OFF_NM + t], dv = ws[OFF_DM + t];
    for (int o = 32; o; o >>= 1) {
        nv += __shfl_xor(nv, o);
        dv += __shfl_xor(dv, o);
    }
    __shared__ float rn[4], rd[4];
    if ((t & 63) == 0) { rn[t >> 6] = nv; rd[t >> 6] = dv; }
    __syncthreads();
    float N = rn[0] + rn[1] + rn[2] + rn[3];
    float D = rd[0] + rd[1] + rd[2] + rd[3];
    float E = N / D;
    float invD = 1.0f / D;
    int i = m * 256 + t;
    out[i] = 2.0f * invD * (ws[OFF_DNT + i] - E * ws[OFF_DDT + i]);
    if (t == 0) out[65536 + m] = 2.0f * invD * (ws[OFF_CN + m] - E * ws[OFF_CD + m]);
    if (m == 0 && t == 1) out[65792] = E * (1.0f / 256.0f);
}

extern "C" void kernel_launch(void* const* d_in, const int* in_sizes, int n_in,
                              void* d_out, int out_size, void* d_ws, size_t ws_size,
                              hipStream_t stream) {
    const float* theta = (const float*)d_in[0];
    const float* coef = (const float*)d_in[1];
    const float* strengths = (const float*)d_in[4];
    float* out = (float*)d_out;
    float* ws = (float*)d_ws;

    k_prep<<<256, 256, 0, stream>>>(theta, ws);
    k_main<<<256, 1024, 0, stream>>>(coef, strengths, ws);
    k_fin<<<256, 256, 0, stream>>>(ws, out);
}

// Round 5
// 87.430 us; speedup vs baseline: 2.6553x; 1.0058x over previous
//
#include <hip/hip_runtime.h>
#include <math.h>

#define HXc 3.0f
#define HZc 0.25f
#define JZc (-1.0f)

// ws layout (float offsets)
#define OFF_TANR 0         // [256*256] tan(theta) row-major [m][l]
#define OFF_TANT 65536     // [256*256] transposed [l][m]
#define OFF_CPR  131072    // [256] per-row product of cos(theta)
#define OFF_DNT  131328    // [512*256] per-(halfblock) partial dN_dtheta/2
#define OFF_DDT  262400    // [512*256]
#define OFF_NM   393472    // [512]
#define OFF_DM   393984    // [512]
#define OFF_CN   394496    // [512]
#define OFF_CD   395008    // [512]

__device__ __forceinline__ float tan_poly(float x) {
    // |x| <= 0.3: tan x = x(1 + y(1/3 + y(2/15 + y(17/315 + y*62/2835)))), y=x^2
    float y = x * x;
    float p = fmaf(y, 62.0f / 2835.0f, 17.0f / 315.0f);
    p = fmaf(y, p, 2.0f / 15.0f);
    p = fmaf(y, p, 1.0f / 3.0f);
    return x * fmaf(y, p, 1.0f);
}

__device__ __forceinline__ float cos_poly(float x) {
    float y = x * x;
    float p = fmaf(y, 1.0f / 40320.0f, -1.0f / 720.0f);
    p = fmaf(y, p, 1.0f / 24.0f);
    p = fmaf(y, p, -0.5f);
    return fmaf(y, p, 1.0f);
}

// block = m, thread = l: tan tables (row + transposed) + per-row cos product.
__global__ __launch_bounds__(256) void k_prep(const float* __restrict__ theta,
                                              float* __restrict__ ws) {
    int m = blockIdx.x, t = threadIdx.x;
    float x = theta[m * 256 + t];
    float tn = tan_poly(x);
    float c = cos_poly(x);
    ws[OFF_TANR + m * 256 + t] = tn;
    ws[OFF_TANT + t * 256 + m] = tn;
    float pr = c;
    for (int o = 32; o; o >>= 1) pr *= __shfl_xor(pr, o);
    __shared__ float pp[4];
    if ((t & 63) == 0) pp[t >> 6] = pr;
    __syncthreads();
    if (t == 0) ws[OFF_CPR + m] = pp[0] * pp[1] * pp[2] * pp[3];
}

// 512 blocks (g = m*2 + half, half owns 128 b's) x 512 threads (8 waves).
// Phase A: forward, thread -> (l-quarter q, local column bl).
// Phase B: gradient, wave = 16-b chunk, lane = 4 consecutive l's.
__global__ __launch_bounds__(512) void k_main(
        const float* __restrict__ coef,
        const float* __restrict__ strengths,
        float* __restrict__ ws) {
    int g = blockIdx.x;
    int m = g >> 1;
    int boff = (g & 1) * 128;
    int tid = threadIdx.x;
    const float* __restrict__ tanR = ws + OFF_TANR;
    const float* __restrict__ tanT = ws + OFF_TANT;
    const float* __restrict__ Cpr = ws + OFF_CPR;

    __shared__ float sLDS[256];          // strengths, padded (s[255]=0)
    __shared__ float tmL[256];           // tan row m
    __shared__ float4 quart[4][128];     // phase-A partials (pw,u,v,z)
    __shared__ float Flds[128], cPlds[128];
    __shared__ float wr[2][4];
    __shared__ float gN[8 * 256];
    __shared__ float gD[8 * 256];

    if (tid < 256) {
        sLDS[tid] = (tid < 255) ? strengths[tid] : 0.0f;
        tmL[tid] = tanR[m * 256 + tid];
    }
    __syncthreads();

    // ---- Phase A ----
    {
        int bl = tid & 127, q = tid >> 7;
        int b = boff + bl;
        int l0 = q * 64;
        float pw = 1.0f, u = 0.0f, v = 0.0f, z = 0.0f, a_prev = 0.0f;
        if (q) {
            int l = l0 - 1;
            float qq = tmL[l] * tanT[l * 256 + b];
            a_prev = (1.0f - qq) * __builtin_amdgcn_rcpf(1.0f + qq);
        }
        for (int l = l0; l < l0 + 64; ++l) {
            float tm = tmL[l];                     // LDS broadcast
            float tb = tanT[l * 256 + b];          // coalesced global (L2)
            float qq = tm * tb;
            float w1 = 1.0f + qq;
            float inv = __builtin_amdgcn_rcpf(w1);
            pw *= w1;
            u = fmaf(tm + tb, inv, u);             // sins/cosd
            float a = (1.0f - qq) * inv;           // coss/cosd
            v += a;
            float sPrev = (l > 0) ? sLDS[l - 1] : 0.0f;
            z = fmaf(sPrev * a_prev, a, z);
            a_prev = a;
        }
        quart[q][bl] = make_float4(pw, u, v, z);
    }
    __syncthreads();

    // ---- Combine quarters: F/cP to LDS, per-halfblock reductions ----
    if (tid < 128) {
        int b = boff + tid;
        float4 A = quart[0][tid], B = quart[1][tid];
        float4 C = quart[2][tid], Dq = quart[3][tid];
        float P = Cpr[m] * Cpr[b] * (A.x * B.x * C.x * Dq.x);
        float U = A.y + B.y + C.y + Dq.y;
        float V = A.z + B.z + C.z + Dq.z;
        float Z = A.w + B.w + C.w + Dq.w;
        float F = HZc * V + HXc * U + JZc * Z;
        float cP = coef[b] * P;
        Flds[tid] = F;
        cPlds[tid] = cP;
        float base = coef[m] * cP;
        float s1 = base, s2 = base * F, s3 = cP, s4 = cP * F;
        for (int o = 32; o; o >>= 1) {
            s1 += __shfl_xor(s1, o);
            s2 += __shfl_xor(s2, o);
            s3 += __shfl_xor(s3, o);
            s4 += __shfl_xor(s4, o);
        }
        if ((tid & 63) == 0) {
            int w = tid >> 6;
            wr[w][0] = s1; wr[w][1] = s2; wr[w][2] = s3; wr[w][3] = s4;
        }
    }
    __syncthreads();
    if (tid == 0) {
        ws[OFF_DM + g] = wr[0][0] + wr[1][0];
        ws[OFF_NM + g] = wr[0][1] + wr[1][1];
        ws[OFF_CD + g] = wr[0][2] + wr[1][2];
        ws[OFF_CN + g] = wr[0][3] + wr[1][3];
    }

    // ---- Phase B: gradient ----
    {
        int w = tid >> 6, lane = tid & 63;
        int l0 = lane * 4;
        float coefm = coef[m];
        float4 tm4 = *(const float4*)&tmL[l0];
        float tm[4] = {tm4.x, tm4.y, tm4.z, tm4.w};
        float sR[4], sL[4];
#pragma unroll
        for (int j = 0; j < 4; ++j) {
            int l = l0 + j;
            sR[j] = sLDS[l];
            sL[j] = (l > 0) ? sLDS[l - 1] : 0.0f;
        }
        float pN[4] = {0.f, 0.f, 0.f, 0.f};
        float pD[4] = {0.f, 0.f, 0.f, 0.f};

        for (int i = 0; i < 16; ++i) {
            int bl = w * 16 + i;
            int b = boff + bl;
            float4 tb4 = *(const float4*)&tanR[b * 256 + l0];
            float tb[4] = {tb4.x, tb4.y, tb4.z, tb4.w};
            float Fv = Flds[bl];
            float base = coefm * cPlds[bl];

            float A[4], S[4], G[4];
#pragma unroll
            for (int j = 0; j < 4; ++j) {
                float qq = tm[j] * tb[j];
                float w1 = 1.0f + qq;
                float inv = __builtin_amdgcn_rcpf(w1);
                A[j] = (1.0f - qq) * inv;
                S[j] = (tm[j] + tb[j]) * inv;
                G[j] = (tm[j] - tb[j]) * inv;
            }
            float aLn = __shfl_up(A[3], 1);
            if (lane == 0) aLn = 0.0f;
            float aRn = __shfl_down(A[0], 1);
            if (lane == 63) aRn = 0.0f;
            float am1[4] = {aLn, A[0], A[1], A[2]};
            float ap1[4] = {A[1], A[2], A[3], aRn};
#pragma unroll
            for (int j = 0; j < 4; ++j) {
                float Gxz = fmaf(HXc, A[j], -HZc * S[j])
                          + fmaf(HZc, A[j], HXc * S[j]) * G[j];
                float K = JZc * fmaf(A[j], G[j], -S[j]);
                float inc = fmaf(sR[j], ap1[j], sL[j] * am1[j]);
                float term = fmaf(Fv, -G[j], fmaf(K, inc, Gxz));
                pN[j] = fmaf(base, term, pN[j]);
                pD[j] = fmaf(base, -G[j], pD[j]);
            }
        }
        ((float4*)gN)[w * 64 + lane] = make_float4(pN[0], pN[1], pN[2], pN[3]);
        ((float4*)gD)[w * 64 + lane] = make_float4(pD[0], pD[1], pD[2], pD[3]);
    }
    __syncthreads();
    if (tid < 256) {
        float sn = 0.0f, sd = 0.0f;
#pragma unroll
        for (int ww = 0; ww < 8; ++ww) {
            sn += gN[ww * 256 + tid];
            sd += gD[ww * 256 + tid];
        }
        ws[OFF_DNT + g * 256 + tid] = sn;
        ws[OFF_DDT + g * 256 + tid] = sd;
    }
}

// 256 blocks x 256 thr: redundant deterministic N/D reduction, then scale.
__global__ __launch_bounds__(256) void k_fin(const float* __restrict__ ws,
                                             float* __restrict__ out) {
    int m = blockIdx.x, t = threadIdx.x;
    float nv = ws[OFF_NM + t] + ws[OFF_NM + 256 + t];
    float dv = ws[OFF_DM + t] + ws[OFF_DM + 256 + t];
    for (int o = 32; o; o >>= 1) {
        nv += __shfl_xor(nv, o);
        dv += __shfl_xor(dv, o);
    }
    __shared__ float rn[4], rd[4];
    if ((t & 63) == 0) { rn[t >> 6] = nv; rd[t >> 6] = dv; }
    __syncthreads();
    float N = rn[0] + rn[1] + rn[2] + rn[3];
    float D = rd[0] + rd[1] + rd[2] + rd[3];
    float E = N / D;
    float invD = 1.0f / D;
    int g0 = m * 2, g1 = m * 2 + 1;
    float sn = ws[OFF_DNT + g0 * 256 + t] + ws[OFF_DNT + g1 * 256 + t];
    float sd = ws[OFF_DDT + g0 * 256 + t] + ws[OFF_DDT + g1 * 256 + t];
    out[m * 256 + t] = 2.0f * invD * (sn - E * sd);
    if (t == 0) {
        float cn = ws[OFF_CN + g0] + ws[OFF_CN + g1];
        float cd = ws[OFF_CD + g0] + ws[OFF_CD + g1];
        out[65536 + m] = 2.0f * invD * (cn - E * cd);
    }
    if (m == 0 && t == 1) out[65792] = E * (1.0f / 256.0f);
}

extern "C" void kernel_launch(void* const* d_in, const int* in_sizes, int n_in,
                              void* d_out, int out_size, void* d_ws, size_t ws_size,
                              hipStream_t stream) {
    const float* theta = (const float*)d_in[0];
    const float* coef = (const float*)d_in[1];
    const float* strengths = (const float*)d_in[4];
    float* out = (float*)d_out;
    float* ws = (float*)d_ws;

    k_prep<<<256, 256, 0, stream>>>(theta, ws);
    k_main<<<512, 512, 0, stream>>>(coef, strengths, ws);
    k_fin<<<256, 256, 0, stream>>>(ws, out);
}